// Round 1
// baseline (490.757 us; speedup 1.0000x reference)
//
#include <hip/hip_runtime.h>

#define N_NODES 100000
#define N_EDGES 1600000
#define D 128

typedef short bf16x8 __attribute__((ext_vector_type(8)));
typedef float f32x4 __attribute__((ext_vector_type(4)));

__device__ __forceinline__ unsigned short f2bf(float x){
  union { float f; unsigned u; } v; v.f = x;
  unsigned r = v.u + 0x7fffu + ((v.u >> 16) & 1u);
  return (unsigned short)(r >> 16);
}

__global__ void zero_counts(int* counts){
  int i = blockIdx.x*256 + threadIdx.x;
  if (i < N_NODES) counts[i] = 0;
}

__global__ void hist_kernel(const int* __restrict__ rows, int* __restrict__ counts){
  int i = blockIdx.x*256 + threadIdx.x;
  if (i < N_EDGES) atomicAdd(&counts[rows[i]], 1);
}

__global__ void scan1(const int* __restrict__ counts, int* __restrict__ row_start,
                      int* __restrict__ bsums){
  __shared__ int s[1024];
  int t = threadIdx.x;
  int idx = blockIdx.x*1024 + t;
  int v = (idx < N_NODES) ? counts[idx] : 0;
  s[t] = v; __syncthreads();
  for (int off = 1; off < 1024; off <<= 1){
    int x = (t >= off) ? s[t-off] : 0;
    __syncthreads();
    s[t] += x;
    __syncthreads();
  }
  if (idx < N_NODES) row_start[idx] = s[t] - v;   // exclusive, pre-block-offset
  if (t == 1023) bsums[blockIdx.x] = s[t];
}

__global__ void scan2(int* bsums, int nb){
  __shared__ int s[128];
  int t = threadIdx.x;
  int v = (t < nb) ? bsums[t] : 0;
  s[t] = v; __syncthreads();
  for (int off = 1; off < 128; off <<= 1){
    int x = (t >= off) ? s[t-off] : 0;
    __syncthreads();
    s[t] += x;
    __syncthreads();
  }
  if (t < nb) bsums[t] = s[t] - v;                // exclusive block offsets
}

__global__ void scan3(int* __restrict__ row_start, int* __restrict__ cursor,
                      const int* __restrict__ bsums){
  int idx = blockIdx.x*1024 + threadIdx.x;
  if (idx < N_NODES){
    int rs = row_start[idx] + bsums[blockIdx.x];
    row_start[idx] = rs;
    cursor[idx] = rs;
  }
}

__global__ void scatter_kernel(const int* __restrict__ rows, const int* __restrict__ cols,
                               const float* __restrict__ vals, int* __restrict__ cursor,
                               int* __restrict__ cols_s, float* __restrict__ vals_s){
  int e = blockIdx.x*256 + threadIdx.x;
  if (e < N_EDGES){
    int r = rows[e];
    int p = atomicAdd(&cursor[r], 1);
    cols_s[p] = cols[e];
    vals_s[p] = vals[e];
  }
}

// WT[c][k] = bf16(W[k][c]) so B-fragments read contiguous k-runs
__global__ void transpose_w(const float* __restrict__ W, unsigned short* __restrict__ WT){
  int idx = blockIdx.x*256 + threadIdx.x;    // 0..16383
  int k = idx >> 7, c = idx & 127;
  WT[c*128 + k] = f2bf(W[idx]);
}

// wave-per-row: agg[row] = sum_e val_e * input[col_e]  (fp32 exact)
__global__ __launch_bounds__(256) void agg_kernel(const float2* __restrict__ input2,
                                                  const int* __restrict__ row_start,
                                                  const int* __restrict__ counts,
                                                  const int* __restrict__ cols_s,
                                                  const float* __restrict__ vals_s,
                                                  float2* __restrict__ agg2){
  int wave = threadIdx.x >> 6, lane = threadIdx.x & 63;
  int row = blockIdx.x*4 + wave;
  int start = row_start[row];
  int n = counts[row];
  float ax = 0.f, ay = 0.f;
  for (int e = start; e < start + n; ++e){
    int c = cols_s[e];
    float v = vals_s[e];
    float2 x = input2[(size_t)c*64 + lane];
    ax = fmaf(v, x.x, ax);
    ay = fmaf(v, x.y, ay);
  }
  float2 o; o.x = ax; o.y = ay;
  agg2[(size_t)row*64 + lane] = o;
}

// out = normalize(BETA*input + (1-BETA)*(agg @ W)) + bias, bf16 MFMA GEMM
// block = 256 threads = 4 waves; 64 rows x 128 cols per block
__global__ __launch_bounds__(256) void final_kernel(const float* __restrict__ agg,
                                                    const float* __restrict__ input,
                                                    const unsigned short* __restrict__ WT,
                                                    const float* __restrict__ bias,
                                                    float* __restrict__ out){
  __shared__ unsigned short Ws[128*136];   // WT[c][k], stride 136 (16B-aligned rows, 2-way banks)
  __shared__ unsigned short As[64*136];    // agg rows bf16
  int t = threadIdx.x;
  int block_row = blockIdx.x * 64;

  const ushort4* WT4 = (const ushort4*)WT;   // 4096 ushort4
  #pragma unroll
  for (int i = 0; i < 16; ++i){
    int idx4 = i*256 + t;
    int c = idx4 >> 5, k4 = idx4 & 31;
    ushort4 w = WT4[idx4];
    *((ushort4*)&Ws[c*136 + k4*4]) = w;
  }
  const float4* agg4 = (const float4*)agg;
  #pragma unroll
  for (int i = 0; i < 8; ++i){
    int flat4 = i*256 + t;                  // 2048 float4 = 64 rows x 32
    int row = flat4 >> 5, k4 = flat4 & 31;
    int grow = block_row + row;
    float4 a = make_float4(0.f, 0.f, 0.f, 0.f);
    if (grow < N_NODES) a = agg4[(size_t)grow*32 + k4];
    ushort4 h;
    h.x = f2bf(a.x); h.y = f2bf(a.y); h.z = f2bf(a.z); h.w = f2bf(a.w);
    *((ushort4*)&As[row*136 + k4*4]) = h;
  }
  __syncthreads();

  int wave = t >> 6, lane = t & 63;
  int q = lane >> 4, n = lane & 15;

  // A-frag: lane holds A[m = lane&15][k = q*8 + j]
  bf16x8 afr[4];
  #pragma unroll
  for (int ks = 0; ks < 4; ++ks)
    afr[ks] = *((const bf16x8*)&As[(wave*16 + n)*136 + ks*32 + q*8]);

  f32x4 acc[8];
  #pragma unroll
  for (int ct = 0; ct < 8; ++ct) acc[ct] = (f32x4){0.f, 0.f, 0.f, 0.f};

  #pragma unroll
  for (int ct = 0; ct < 8; ++ct){
    #pragma unroll
    for (int ks = 0; ks < 4; ++ks){
      // B-frag: lane holds B[k = q*8 + j][col n] = Ws[ct*16+n][k]
      bf16x8 bfr = *((const bf16x8*)&Ws[(ct*16 + n)*136 + ks*32 + q*8]);
      acc[ct] = __builtin_amdgcn_mfma_f32_16x16x32_bf16(afr[ks], bfr, acc[ct], 0, 0, 0);
    }
  }

  // C/D: col = lane&15 (+ct*16), row = q*4 + reg (+wave*16)
  int base_row = block_row + wave*16 + q*4;
  float v[8][4];
  float s[4] = {0.f, 0.f, 0.f, 0.f};
  #pragma unroll
  for (int reg = 0; reg < 4; ++reg){
    int grow = base_row + reg;
    const float* inrow = input + (size_t)grow * D;
    #pragma unroll
    for (int ct = 0; ct < 8; ++ct){
      float inp = (grow < N_NODES) ? inrow[ct*16 + n] : 0.f;
      float val = fmaf(0.999f, acc[ct][reg], 0.001f * inp);
      v[ct][reg] = val;
      s[reg] = fmaf(val, val, s[reg]);
    }
  }
  #pragma unroll
  for (int reg = 0; reg < 4; ++reg){
    float x = s[reg];
    x += __shfl_xor(x, 1);
    x += __shfl_xor(x, 2);
    x += __shfl_xor(x, 4);
    x += __shfl_xor(x, 8);
    s[reg] = x;
  }
  #pragma unroll
  for (int reg = 0; reg < 4; ++reg){
    int grow = base_row + reg;
    if (grow >= N_NODES) continue;
    float scale = 1.f / fmaxf(sqrtf(s[reg]), 1e-12f);
    float* outrow = out + (size_t)grow * D;
    #pragma unroll
    for (int ct = 0; ct < 8; ++ct){
      outrow[ct*16 + n] = fmaf(v[ct][reg], scale, bias[ct*16 + n]);
    }
  }
}

extern "C" void kernel_launch(void* const* d_in, const int* in_sizes, int n_in,
                              void* d_out, int out_size, void* d_ws, size_t ws_size,
                              hipStream_t stream){
  const float* input  = (const float*)d_in[0];
  const int*   erows  = (const int*)d_in[1];
  const int*   ecols  = (const int*)d_in[2];
  const float* evals  = (const float*)d_in[3];
  const float* weight = (const float*)d_in[4];
  const float* bias   = (const float*)d_in[5];
  float* out = (float*)d_out;

  const size_t NA = 100352;                       // 98*1024, padded node count
  int*   counts    = (int*)d_ws;
  int*   row_start = counts + NA;
  int*   cursor    = row_start + NA;
  int*   bsums     = cursor + NA;                 // 128 slots
  int*   cols_s    = bsums + 128;
  float* vals_s    = (float*)(cols_s + N_EDGES);
  float* agg       = vals_s + N_EDGES;            // N*D floats
  unsigned short* WTg = (unsigned short*)(agg + (size_t)N_NODES * D);  // 16384 ushort

  zero_counts<<<(N_NODES+255)/256, 256, 0, stream>>>(counts);
  hist_kernel<<<(N_EDGES+255)/256, 256, 0, stream>>>(erows, counts);
  scan1<<<98, 1024, 0, stream>>>(counts, row_start, bsums);
  scan2<<<1, 128, 0, stream>>>(bsums, 98);
  scan3<<<98, 1024, 0, stream>>>(row_start, cursor, bsums);
  scatter_kernel<<<(N_EDGES+255)/256, 256, 0, stream>>>(erows, ecols, evals, cursor, cols_s, vals_s);
  transpose_w<<<64, 256, 0, stream>>>(weight, WTg);
  agg_kernel<<<N_NODES/4, 256, 0, stream>>>((const float2*)input, row_start, counts, cols_s, vals_s, (float2*)agg);
  final_kernel<<<(N_NODES + 63)/64, 256, 0, stream>>>(agg, input, WTg, bias, out);
}

// Round 2
// 454.098 us; speedup vs baseline: 1.0807x; 1.0807x over previous
//
#include <hip/hip_runtime.h>

#define N_NODES 100000
#define N_EDGES 1600000
#define D 128

typedef short bf16x8 __attribute__((ext_vector_type(8)));
typedef float f32x4 __attribute__((ext_vector_type(4)));

__device__ __forceinline__ unsigned short f2bf(float x){
  union { float f; unsigned u; } v; v.f = x;
  unsigned r = v.u + 0x7fffu + ((v.u >> 16) & 1u);
  return (unsigned short)(r >> 16);
}

__global__ void hist_kernel(const int4* __restrict__ rows4, int* __restrict__ counts){
  int i = blockIdx.x*256 + threadIdx.x;
  if (i < N_EDGES/4){
    int4 r = rows4[i];
    atomicAdd(&counts[r.x], 1);
    atomicAdd(&counts[r.y], 1);
    atomicAdd(&counts[r.z], 1);
    atomicAdd(&counts[r.w], 1);
  }
}

__global__ void scan1(const int* __restrict__ counts, int* __restrict__ row_start,
                      int* __restrict__ bsums){
  __shared__ int s[1024];
  int t = threadIdx.x;
  int idx = blockIdx.x*1024 + t;
  int v = (idx < N_NODES) ? counts[idx] : 0;
  s[t] = v; __syncthreads();
  for (int off = 1; off < 1024; off <<= 1){
    int x = (t >= off) ? s[t-off] : 0;
    __syncthreads();
    s[t] += x;
    __syncthreads();
  }
  if (idx < N_NODES) row_start[idx] = s[t] - v;   // exclusive, pre-block-offset
  if (t == 1023) bsums[blockIdx.x] = s[t];
}

__global__ void scan2(int* bsums, int nb){
  __shared__ int s[128];
  int t = threadIdx.x;
  int v = (t < nb) ? bsums[t] : 0;
  s[t] = v; __syncthreads();
  for (int off = 1; off < 128; off <<= 1){
    int x = (t >= off) ? s[t-off] : 0;
    __syncthreads();
    s[t] += x;
    __syncthreads();
  }
  if (t < nb) bsums[t] = s[t] - v;                // exclusive block offsets
}

__global__ void scan3(int* __restrict__ row_start, int* __restrict__ cursor,
                      const int* __restrict__ bsums){
  int idx = blockIdx.x*1024 + threadIdx.x;
  if (idx < N_NODES){
    int rs = row_start[idx] + bsums[blockIdx.x];
    row_start[idx] = rs;
    cursor[idx] = rs;
  }
}

// edges_s[p] = {col, float_bits(val)} — one 8B scattered store per edge
__global__ void scatter_kernel(const int4* __restrict__ rows4, const int4* __restrict__ cols4,
                               const float4* __restrict__ vals4, int* __restrict__ cursor,
                               int2* __restrict__ edges_s){
  int i = blockIdx.x*256 + threadIdx.x;
  if (i < N_EDGES/4){
    int4 r = rows4[i];
    int4 c = cols4[i];
    float4 v = vals4[i];
    int p0 = atomicAdd(&cursor[r.x], 1);
    int p1 = atomicAdd(&cursor[r.y], 1);
    int p2 = atomicAdd(&cursor[r.z], 1);
    int p3 = atomicAdd(&cursor[r.w], 1);
    edges_s[p0] = make_int2(c.x, __float_as_int(v.x));
    edges_s[p1] = make_int2(c.y, __float_as_int(v.y));
    edges_s[p2] = make_int2(c.z, __float_as_int(v.z));
    edges_s[p3] = make_int2(c.w, __float_as_int(v.w));
  }
}

// WT[c][k] = bf16(W[k][c]) so B-fragments read contiguous k-runs
__global__ void transpose_w(const float* __restrict__ W, unsigned short* __restrict__ WT){
  int idx = blockIdx.x*256 + threadIdx.x;    // 0..16383
  int k = idx >> 7, c = idx & 127;
  WT[c*128 + k] = f2bf(W[idx]);
}

// 32-lane group per row, float4 per lane (512B row), unroll x4 for MLP.
// agg output stored as bf16 (ushort4 per lane).
__global__ __launch_bounds__(256) void agg_kernel(const float4* __restrict__ input4,
                                                  const int* __restrict__ row_start,
                                                  const int* __restrict__ counts,
                                                  const int2* __restrict__ edges,
                                                  ushort4* __restrict__ aggb){
  int g = threadIdx.x >> 5, l = threadIdx.x & 31;
  int row = blockIdx.x*8 + g;                 // grid = 12500 blocks, exact
  int start = row_start[row];
  int n = counts[row];
  int e = start, end = start + n;

  float4 a0 = make_float4(0.f,0.f,0.f,0.f);
  float4 a1 = make_float4(0.f,0.f,0.f,0.f);
  float4 a2 = make_float4(0.f,0.f,0.f,0.f);
  float4 a3 = make_float4(0.f,0.f,0.f,0.f);

  for (; e + 4 <= end; e += 4){
    int2 e0 = edges[e+0];
    int2 e1 = edges[e+1];
    int2 e2 = edges[e+2];
    int2 e3 = edges[e+3];
    float4 x0 = input4[(size_t)e0.x*32 + l];
    float4 x1 = input4[(size_t)e1.x*32 + l];
    float4 x2 = input4[(size_t)e2.x*32 + l];
    float4 x3 = input4[(size_t)e3.x*32 + l];
    float v0 = __int_as_float(e0.y), v1 = __int_as_float(e1.y);
    float v2 = __int_as_float(e2.y), v3 = __int_as_float(e3.y);
    a0.x = fmaf(v0, x0.x, a0.x); a0.y = fmaf(v0, x0.y, a0.y);
    a0.z = fmaf(v0, x0.z, a0.z); a0.w = fmaf(v0, x0.w, a0.w);
    a1.x = fmaf(v1, x1.x, a1.x); a1.y = fmaf(v1, x1.y, a1.y);
    a1.z = fmaf(v1, x1.z, a1.z); a1.w = fmaf(v1, x1.w, a1.w);
    a2.x = fmaf(v2, x2.x, a2.x); a2.y = fmaf(v2, x2.y, a2.y);
    a2.z = fmaf(v2, x2.z, a2.z); a2.w = fmaf(v2, x2.w, a2.w);
    a3.x = fmaf(v3, x3.x, a3.x); a3.y = fmaf(v3, x3.y, a3.y);
    a3.z = fmaf(v3, x3.z, a3.z); a3.w = fmaf(v3, x3.w, a3.w);
  }
  for (; e < end; ++e){
    int2 ee = edges[e];
    float4 x = input4[(size_t)ee.x*32 + l];
    float v = __int_as_float(ee.y);
    a0.x = fmaf(v, x.x, a0.x); a0.y = fmaf(v, x.y, a0.y);
    a0.z = fmaf(v, x.z, a0.z); a0.w = fmaf(v, x.w, a0.w);
  }
  float4 s;
  s.x = (a0.x + a1.x) + (a2.x + a3.x);
  s.y = (a0.y + a1.y) + (a2.y + a3.y);
  s.z = (a0.z + a1.z) + (a2.z + a3.z);
  s.w = (a0.w + a1.w) + (a2.w + a3.w);
  ushort4 h;
  h.x = f2bf(s.x); h.y = f2bf(s.y); h.z = f2bf(s.z); h.w = f2bf(s.w);
  aggb[(size_t)row*32 + l] = h;
}

// out = normalize(BETA*input + (1-BETA)*(agg @ W)) + bias, bf16 MFMA GEMM
// block = 256 threads = 4 waves; 64 rows x 128 cols per block
__global__ __launch_bounds__(256) void final_kernel(const ushort4* __restrict__ aggb,
                                                    const float* __restrict__ input,
                                                    const unsigned short* __restrict__ WT,
                                                    const float* __restrict__ bias,
                                                    float* __restrict__ out){
  __shared__ unsigned short Ws[128*136];   // WT[c][k], stride 136
  __shared__ unsigned short As[64*136];    // agg rows bf16
  int t = threadIdx.x;
  int block_row = blockIdx.x * 64;

  const ushort4* WT4 = (const ushort4*)WT;   // 4096 ushort4
  #pragma unroll
  for (int i = 0; i < 16; ++i){
    int idx4 = i*256 + t;
    int c = idx4 >> 5, k4 = idx4 & 31;
    ushort4 w = WT4[idx4];
    *((ushort4*)&Ws[c*136 + k4*4]) = w;
  }
  #pragma unroll
  for (int i = 0; i < 8; ++i){
    int idx4 = i*256 + t;                   // 2048 ushort4 = 64 rows x 32
    int row = idx4 >> 5, k4 = idx4 & 31;
    int grow = block_row + row;
    ushort4 h = make_ushort4(0,0,0,0);
    if (grow < N_NODES) h = aggb[(size_t)grow*32 + k4];
    *((ushort4*)&As[row*136 + k4*4]) = h;
  }
  __syncthreads();

  int wave = t >> 6, lane = t & 63;
  int q = lane >> 4, n = lane & 15;

  // A-frag: lane holds A[m = lane&15][k = q*8 + j]
  bf16x8 afr[4];
  #pragma unroll
  for (int ks = 0; ks < 4; ++ks)
    afr[ks] = *((const bf16x8*)&As[(wave*16 + n)*136 + ks*32 + q*8]);

  f32x4 acc[8];
  #pragma unroll
  for (int ct = 0; ct < 8; ++ct) acc[ct] = (f32x4){0.f, 0.f, 0.f, 0.f};

  #pragma unroll
  for (int ct = 0; ct < 8; ++ct){
    #pragma unroll
    for (int ks = 0; ks < 4; ++ks){
      bf16x8 bfr = *((const bf16x8*)&Ws[(ct*16 + n)*136 + ks*32 + q*8]);
      acc[ct] = __builtin_amdgcn_mfma_f32_16x16x32_bf16(afr[ks], bfr, acc[ct], 0, 0, 0);
    }
  }

  // C/D: col = lane&15 (+ct*16), row = q*4 + reg (+wave*16)
  int base_row = block_row + wave*16 + q*4;
  float v[8][4];
  float s[4] = {0.f, 0.f, 0.f, 0.f};
  #pragma unroll
  for (int reg = 0; reg < 4; ++reg){
    int grow = base_row + reg;
    const float* inrow = input + (size_t)grow * D;
    #pragma unroll
    for (int ct = 0; ct < 8; ++ct){
      float inp = (grow < N_NODES) ? inrow[ct*16 + n] : 0.f;
      float val = fmaf(0.999f, acc[ct][reg], 0.001f * inp);
      v[ct][reg] = val;
      s[reg] = fmaf(val, val, s[reg]);
    }
  }
  #pragma unroll
  for (int reg = 0; reg < 4; ++reg){
    float x = s[reg];
    x += __shfl_xor(x, 1);
    x += __shfl_xor(x, 2);
    x += __shfl_xor(x, 4);
    x += __shfl_xor(x, 8);
    s[reg] = x;
  }
  #pragma unroll
  for (int reg = 0; reg < 4; ++reg){
    int grow = base_row + reg;
    if (grow >= N_NODES) continue;
    float scale = 1.f / fmaxf(sqrtf(s[reg]), 1e-12f);
    float* outrow = out + (size_t)grow * D;
    #pragma unroll
    for (int ct = 0; ct < 8; ++ct){
      outrow[ct*16 + n] = fmaf(v[ct][reg], scale, bias[ct*16 + n]);
    }
  }
}

extern "C" void kernel_launch(void* const* d_in, const int* in_sizes, int n_in,
                              void* d_out, int out_size, void* d_ws, size_t ws_size,
                              hipStream_t stream){
  const float* input  = (const float*)d_in[0];
  const int*   erows  = (const int*)d_in[1];
  const int*   ecols  = (const int*)d_in[2];
  const float* evals  = (const float*)d_in[3];
  const float* weight = (const float*)d_in[4];
  const float* bias   = (const float*)d_in[5];
  float* out = (float*)d_out;

  const size_t NA = 100352;                       // 98*1024, padded node count
  int*   counts    = (int*)d_ws;
  int*   row_start = counts + NA;
  int*   cursor    = row_start + NA;
  int*   bsums     = cursor + NA;                 // 128 slots
  int2*  edges_s   = (int2*)(bsums + 128);        // 1.6M int2 (8B-aligned)
  ushort4* aggb    = (ushort4*)(edges_s + N_EDGES);  // N*32 ushort4 (bf16 agg)
  unsigned short* WTg = (unsigned short*)(aggb + (size_t)N_NODES * 32);

  hipMemsetAsync(counts, 0, NA * sizeof(int), stream);
  hist_kernel<<<(N_EDGES/4 + 255)/256, 256, 0, stream>>>((const int4*)erows, counts);
  scan1<<<98, 1024, 0, stream>>>(counts, row_start, bsums);
  scan2<<<1, 128, 0, stream>>>(bsums, 98);
  scan3<<<98, 1024, 0, stream>>>(row_start, cursor, bsums);
  scatter_kernel<<<(N_EDGES/4 + 255)/256, 256, 0, stream>>>(
      (const int4*)erows, (const int4*)ecols, (const float4*)evals, cursor, edges_s);
  transpose_w<<<64, 256, 0, stream>>>(weight, WTg);
  agg_kernel<<<N_NODES/8, 256, 0, stream>>>((const float4*)input, row_start, counts, edges_s, aggb);
  final_kernel<<<(N_NODES + 63)/64, 256, 0, stream>>>(aggb, input, WTg, bias, out);
}